// Round 5
// baseline (659.439 us; speedup 1.0000x reference)
//
#include <hip/hip_runtime.h>
#include <hip/hip_bf16.h>

#define DM 1024
#define HID 64
#define NSTEP 6
#define RSTEP (1.0f/6.0f)

using short8  = __attribute__((ext_vector_type(8))) short;
using short4v = __attribute__((ext_vector_type(4))) short;
using f32x4   = __attribute__((ext_vector_type(4))) float;

// workspace byte offsets
#define WS_W1P 0          // 1024x64 bf16 packed A-frags (131072 B)
#define WS_W2P 131072     // 64x1024 bf16 packed A-frags (131072 B)
#define WS_GP  262144     // 64x64 bf16 packed A-frags (8192 B)
#define WS_U   270336     // 64 f32  (u = b2 @ W1k)

// LDS: per-WAVE private slice (no cross-wave sharing -> no barriers).
// slice = zh [16 rows][2048 B] bf16 XOR-swizzled (32768)
//       + H0 [16][144 B] (2304) + H1 [16][144 B] (2304) = 37376 B
// 4 waves/block -> 149504 B -> 1 block/CU.
#define ZPITCH 2048
#define L_H0 32768
#define L_H1 35072
#define WSLICE 37376
#define LDS_TOTAL (4 * WSLICE)
#define HP 144

// intra-wave ordering only: LDS ops are in-order within a wave; this fence
// just stops the compiler migrating ds ops across phases. No s_barrier!
#define FENCE() asm volatile("s_waitcnt lgkmcnt(0)" ::: "memory")

__device__ __forceinline__ float bf2f(short s) {
    union { unsigned u; float f; } v;
    v.u = ((unsigned)(unsigned short)s) << 16;
    return v.f;
}
__device__ __forceinline__ short f2bf(float f) {   // RNE via HW cvt
    __hip_bfloat16 h = __float2bfloat16(f);
    short s;
    __builtin_memcpy(&s, &h, 2);
    return s;
}
__device__ __forceinline__ float ftanh(float x) {
    x = fminf(fmaxf(x, -10.f), 10.f);
    float e = __expf(2.f * x);
    return __fdividef(e - 1.f, e + 1.f);
}

// ---------------- prep: pack weights to MFMA fragment layout ----------------
__global__ void k_prep(const float* __restrict__ W1, const float* __restrict__ W2,
                       const float* __restrict__ b2,
                       short* __restrict__ W1P, short* __restrict__ W2P,
                       short* __restrict__ GP, float* __restrict__ U) {
    __shared__ float red[4][64];
    int b = blockIdx.x;
    int t = threadIdx.x;           // 256 threads
    int l = t & 63, q4 = t >> 6;
    if (b < 128) {                 // W1k (1024x64) -> W1P[kk<32][c<4][l][8]
        if (t < 64) {
            int kk = b >> 2, c = b & 3;
            int col = c * 16 + (l & 15);
            int kb = kk * 32 + ((l >> 4) << 3);
            short8 v;
            #pragma unroll
            for (int i = 0; i < 8; ++i) v[i] = f2bf(W1[(kb + i) * HID + col]);
            *(short8*)(W1P + (((kk * 4 + c) * 64) + l) * 8) = v;
        }
    } else if (b < 256) {          // W2 (64x1024) -> W2P[kk2<2][ct<64][l][8]
        if (t < 64) {
            int bb = b - 128;
            int kk2 = bb >> 6, ct = bb & 63;
            int col = ct * 16 + (l & 15);
            int kb = kk2 * 32 + ((l >> 4) << 3);
            short8 v;
            #pragma unroll
            for (int i = 0; i < 8; ++i) v[i] = f2bf(W2[(kb + i) * DM + col]);
            *(short8*)(W2P + (((kk2 * 64 + ct) * 64) + l) * 8) = v;
        }
    } else if (b < 320) {          // G[j][i] = sum_d W2[j][d]*W1[d][i]; j = b-256
        int j = b - 256;
        float acc = 0.f;
        #pragma unroll 8
        for (int d = q4 * 256; d < q4 * 256 + 256; ++d)
            acc += W2[j * DM + d] * W1[d * HID + l];
        red[q4][l] = acc;
        __syncthreads();
        if (t < 64) {
            float a = red[0][l] + red[1][l] + red[2][l] + red[3][l];
            int kk = j >> 5, lk = (j >> 3) & 3, ii = j & 7, c = l >> 4, lo = l & 15;
            GP[(((kk * 4 + c) * 64) + lk * 16 + lo) * 8 + ii] = f2bf(a);
        }
    } else {                       // u[i] = sum_d b2[d]*W1[d][i]
        float acc = 0.f;
        #pragma unroll 8
        for (int d = q4 * 256; d < q4 * 256 + 256; ++d)
            acc += b2[d] * W1[d * HID + l];
        red[q4][l] = acc;
        __syncthreads();
        if (t < 64) U[l] = red[0][l] + red[1][l] + red[2][l] + red[3][l];
    }
}

// ---------------- fused RK4 neural-ODE kernel (barrier-free) ----------------
// Each WAVE owns 16 rows of z, end to end: GEMM1, all 4 RK4 stages, GEMM2.
// No inter-wave communication at all -> zero s_barrier. Cross-LANE data
// (MFMA B-frag relayouts) goes through the wave's private LDS slice; the
// per-wave in-order DS pipe gives RAW ordering for free.
// z master = zh (bf16 in LDS, XOR-swizzled) + zlo (bf16 residual in regs:
// lane owns row l15, cols {16ct + hq*4 + j}, ct=0..63 -> short4v zlo[64],
// statically indexed only).
// MFMA: A = packed weights (M = out-col), B = z/H rows (N = row).
// D: m = (lane>>4)*4+reg (out-col), n = lane&15 (row).
// waves_per_eu(1,1): 1 block/CU anyway (LDS); open the full unified
// VGPR+AGPR budget so zlo[] lands in AGPRs, never scratch (R4 lesson).
__global__ __launch_bounds__(256) __attribute__((amdgpu_waves_per_eu(1, 1)))
void k_ode(
        const float* __restrict__ X, const float* __restrict__ W1,
        const float* __restrict__ b1, const float* __restrict__ b2,
        const short* __restrict__ W1P, const short* __restrict__ W2P,
        const short* __restrict__ GP, const float* __restrict__ U,
        float* __restrict__ OUT) {
    extern __shared__ char smem[];
    const int t = threadIdx.x;
    const int lane = t & 63;
    const int w = t >> 6;                    // wave id 0..3
    const int hq = lane >> 4;
    const int l15 = lane & 15;
    const int swz = (l15 & 7) << 4;          // row XOR swizzle (16B granule)
    char* zsl = smem + w * WSLICE;           // this wave's zh slice
    char* h0  = zsl + L_H0;
    char* h1  = zsl + L_H1;
    const size_t myrow = (size_t)blockIdx.x * 64 + w * 16 + l15;
    const int zrow = l15 * ZPITCH;

    // per-lane constants for all 4 hid col-tiles
    f32x4 b1c[4], w1c[4], u4c[4];
    short8 gfr[2][4];
    #pragma unroll
    for (int c = 0; c < 4; ++c) {
        int col = c * 16 + hq * 4;
        b1c[c] = *(const f32x4*)(b1 + col);
        w1c[c] = *(const f32x4*)(W1 + DM * HID + col);   // time row of W1
        u4c[c] = *(const f32x4*)(U + col);
        #pragma unroll
        for (int kk2 = 0; kk2 < 2; ++kk2)
            gfr[kk2][c] = *(const short8*)(GP + ((kk2 * 4 + c) * 64 + lane) * 8);
    }

    // ---- load owned x slice -> zlo regs (residual) + zh LDS (bf16 hi) ----
    short4v zlo[64];
    {
        const float* xrow = X + myrow * DM;
        #pragma unroll
        for (int ct = 0; ct < 64; ++ct) {
            int col = ct * 16 + hq * 4;
            f32x4 v = *(const f32x4*)(xrow + col);
            short4v hh, ll;
            #pragma unroll
            for (int j = 0; j < 4; ++j) {
                short h = f2bf(v[j]);
                hh[j] = h;
                ll[j] = f2bf(v[j] - bf2f(h));
            }
            zlo[ct] = ll;
            *(short4v*)(zsl + zrow + ((col * 2) ^ swz)) = hh;
        }
    }
    FENCE();

    #pragma unroll 1
    for (int s = 0; s < NSTEP; ++s) {
        const float tcur = RSTEP * (float)s;

        // P1: szc[c] = (z @ W1k) for all 4 hid col-tiles; K=1024, 32 slices.
        // One zh B-frag per K-slice shared by 4 independent MFMA chains.
        f32x4 szc[4];
        {
            const short8* wp = (const short8*)W1P + lane;
            f32x4 a0 = (f32x4){0.f,0.f,0.f,0.f}, a1 = a0, a2 = a0, a3 = a0;
            #pragma unroll
            for (int kk = 0; kk < 32; ++kk) {
                short8 zf = *(const short8*)(zsl + zrow + (((kk << 6) + (hq << 4)) ^ swz));
                a0 = __builtin_amdgcn_mfma_f32_16x16x32_bf16(wp[(kk * 4 + 0) * 64], zf, a0, 0, 0, 0);
                a1 = __builtin_amdgcn_mfma_f32_16x16x32_bf16(wp[(kk * 4 + 1) * 64], zf, a1, 0, 0, 0);
                a2 = __builtin_amdgcn_mfma_f32_16x16x32_bf16(wp[(kk * 4 + 2) * 64], zf, a2, 0, 0, 0);
                a3 = __builtin_amdgcn_mfma_f32_16x16x32_bf16(wp[(kk * 4 + 3) * 64], zf, a3, 0, 0, 0);
            }
            szc[0] = a0; szc[1] = a1; szc[2] = a2; szc[3] = a3;
        }

        // P2: stage 1  H1 = tanh(sz + t*w1t + b1) -> H0
        f32x4 hsum[4];
        #pragma unroll
        for (int c = 0; c < 4; ++c) {
            short4v hc;
            #pragma unroll
            for (int j = 0; j < 4; ++j) {
                float T = szc[c][j] + tcur * w1c[c][j] + b1c[c][j];
                float h = ftanh(T);
                hsum[c][j] = h;
                hc[j] = f2bf(h);
            }
            *(short4v*)(h0 + l15 * HP + ((c * 32 + hq * 8) ^ swz)) = hc;
        }
        FENCE();

        // stages 2..4 via tiny H@G (G = W2@W1k); H ping-pongs H0->H1->H0->H1
        #pragma unroll
        for (int st = 0; st < 3; ++st) {
            const float c_i = (st == 2) ? RSTEP : (0.5f * RSTEP);
            const float t_i = tcur + ((st == 2) ? RSTEP : (0.5f * RSTEP));
            const float w_i = (st == 2) ? 1.f : 2.f;
            char* rb = (st & 1) ? h1 : h0;
            char* wb = (st & 1) ? h0 : h1;

            short8 hf0 = *(const short8*)(rb + l15 * HP + (((hq << 4)) ^ swz));
            short8 hf1 = *(const short8*)(rb + l15 * HP + ((64 + (hq << 4)) ^ swz));
            #pragma unroll
            for (int c = 0; c < 4; ++c) {
                f32x4 dd = (f32x4){0.f, 0.f, 0.f, 0.f};
                dd = __builtin_amdgcn_mfma_f32_16x16x32_bf16(gfr[0][c], hf0, dd, 0, 0, 0);
                dd = __builtin_amdgcn_mfma_f32_16x16x32_bf16(gfr[1][c], hf1, dd, 0, 0, 0);
                short4v hc;
                #pragma unroll
                for (int j = 0; j < 4; ++j) {
                    float T = szc[c][j] + c_i * (dd[j] + u4c[c][j]) + t_i * w1c[c][j] + b1c[c][j];
                    float h = ftanh(T);
                    hsum[c][j] += w_i * h;
                    hc[j] = (st < 2) ? f2bf(h) : f2bf(hsum[c][j] * (RSTEP / 6.f));
                }
                *(short4v*)(wb + l15 * HP + ((c * 32 + hq * 8) ^ swz)) = hc;
            }
            FENCE();
        }

        // P6: z += Hb @ W2 + h*b2  (Hb in H1; all 64 col-tiles, own 16 rows)
        {
            short8 hb0 = *(const short8*)(h1 + l15 * HP + (((hq << 4)) ^ swz));
            short8 hb1 = *(const short8*)(h1 + l15 * HP + ((64 + (hq << 4)) ^ swz));
            const short8* w2p8 = (const short8*)W2P;

            if (s < NSTEP - 1) {
                #pragma unroll
                for (int ct = 0; ct < 64; ++ct) {
                    short8 wa = w2p8[ct * 64 + lane];
                    short8 wb2 = w2p8[(64 + ct) * 64 + lane];
                    f32x4 p = (f32x4){0.f, 0.f, 0.f, 0.f};
                    p = __builtin_amdgcn_mfma_f32_16x16x32_bf16(wa, hb0, p, 0, 0, 0);
                    p = __builtin_amdgcn_mfma_f32_16x16x32_bf16(wb2, hb1, p, 0, 0, 0);
                    int col = ct * 16 + hq * 4;
                    f32x4 b2v = *(const f32x4*)(b2 + col);
                    int a = zrow + ((col * 2) ^ swz);
                    short4v oh = *(short4v*)(zsl + a);
                    short4v ll = zlo[ct], nh, nl;
                    #pragma unroll
                    for (int j = 0; j < 4; ++j) {
                        float v = bf2f(oh[j]) + bf2f(ll[j]) + p[j] + RSTEP * b2v[j];
                        short h = f2bf(v);
                        nh[j] = h;
                        nl[j] = f2bf(v - bf2f(h));
                    }
                    *(short4v*)(zsl + a) = nh;
                    zlo[ct] = nl;
                }
                FENCE();
            } else {   // last step: final z straight to OUT (f32)
                float* orow = OUT + myrow * DM;
                #pragma unroll
                for (int ct = 0; ct < 64; ++ct) {
                    short8 wa = w2p8[ct * 64 + lane];
                    short8 wb2 = w2p8[(64 + ct) * 64 + lane];
                    f32x4 p = (f32x4){0.f, 0.f, 0.f, 0.f};
                    p = __builtin_amdgcn_mfma_f32_16x16x32_bf16(wa, hb0, p, 0, 0, 0);
                    p = __builtin_amdgcn_mfma_f32_16x16x32_bf16(wb2, hb1, p, 0, 0, 0);
                    int col = ct * 16 + hq * 4;
                    f32x4 b2v = *(const f32x4*)(b2 + col);
                    short4v oh = *(short4v*)(zsl + zrow + ((col * 2) ^ swz));
                    short4v ll = zlo[ct];
                    f32x4 v;
                    #pragma unroll
                    for (int j = 0; j < 4; ++j)
                        v[j] = bf2f(oh[j]) + bf2f(ll[j]) + p[j] + RSTEP * b2v[j];
                    *(f32x4*)(orow + col) = v;
                }
            }
        }
    }
}

extern "C" void kernel_launch(void* const* d_in, const int* in_sizes, int n_in,
                              void* d_out, int out_size, void* d_ws, size_t ws_size,
                              hipStream_t stream) {
    (void)in_sizes; (void)n_in; (void)out_size; (void)ws_size;
    const float* X  = (const float*)d_in[0];
    const float* W1 = (const float*)d_in[1];
    const float* b1 = (const float*)d_in[2];
    const float* W2 = (const float*)d_in[3];
    const float* b2 = (const float*)d_in[4];
    float* OUT = (float*)d_out;
    short* W1P = (short*)((char*)d_ws + WS_W1P);
    short* W2P = (short*)((char*)d_ws + WS_W2P);
    short* GP  = (short*)((char*)d_ws + WS_GP);
    float* U   = (float*)((char*)d_ws + WS_U);

    hipFuncSetAttribute(reinterpret_cast<const void*>(k_ode),
                        hipFuncAttributeMaxDynamicSharedMemorySize, LDS_TOTAL);

    k_prep<<<321, 256, 0, stream>>>(W1, W2, b2, W1P, W2P, GP, U);
    k_ode<<<256, 256, LDS_TOTAL, stream>>>(X, W1, b1, b2, W1P, W2P, GP, U, OUT);
}

// Round 6
// 152.183 us; speedup vs baseline: 4.3332x; 4.3332x over previous
//
#include <hip/hip_runtime.h>
#include <hip/hip_bf16.h>

#define DM 1024
#define HID 64
#define NSTEP 6
#define RSTEP (1.0f/6.0f)

using short8  = __attribute__((ext_vector_type(8))) short;
using short4v = __attribute__((ext_vector_type(4))) short;
using f32x4   = __attribute__((ext_vector_type(4))) float;

// workspace byte offsets
#define WS_W1P 0          // 1024x64 bf16 packed A-frags (131072 B)
#define WS_W2P 131072     // 64x1024 bf16 packed A-frags (131072 B)
#define WS_GP  262144     // 64x64 bf16 packed A-frags (8192 B)
#define WS_U   270336     // 64 f32  (u = b2 @ W1k)

// LDS byte offsets (total 76544 B -> 2 blocks/CU on 160 KiB LDS)
#define L_ZF 0            // [16][1024] f32 z master, 16B-granule XOR swizzle (65536)
#define L_H0 65536        // H ping  [16][72] bf16, pitch 144 (2304)
#define L_H1 67840        // H pong
#define L_HB 70144        // Hb = (h/6)*Hsum
#define L_B2 72448        // b2 staged f32[1024] (4096)
#define LDS_TOTAL 76544
#define HP 144

// LDS-only barrier: order LDS ops, do NOT drain vmcnt (weight loads stay
// in flight across barriers; cross-wave data passes only through LDS).
#define BAR() asm volatile("s_waitcnt lgkmcnt(0)\n\ts_barrier" ::: "memory")

__device__ __forceinline__ short f2bf(float f) {   // RNE via HW cvt
    __hip_bfloat16 h = __float2bfloat16(f);
    short s;
    __builtin_memcpy(&s, &h, 2);
    return s;
}
__device__ __forceinline__ float ftanh(float x) {
    x = fminf(fmaxf(x, -10.f), 10.f);
    float e = __expf(2.f * x);
    return __fdividef(e - 1.f, e + 1.f);
}

// ---------------- prep: pack weights to MFMA fragment layout ----------------
// A-frag layout for mfma_f32_16x16x32_bf16: lane l holds M-row (l&15),
// k = (l>>4)*8 + i (8 consecutive k). Packed so each lane loads one short8.
__global__ void k_prep(const float* __restrict__ W1, const float* __restrict__ W2,
                       const float* __restrict__ b2,
                       short* __restrict__ W1P, short* __restrict__ W2P,
                       short* __restrict__ GP, float* __restrict__ U) {
    __shared__ float red[4][64];
    int b = blockIdx.x;
    int t = threadIdx.x;           // 256 threads
    int l = t & 63, q4 = t >> 6;
    if (b < 128) {                 // W1k (1024x64) -> W1P[kk<32][c<4][l][8]
        if (t < 64) {
            int kk = b >> 2, c = b & 3;
            int col = c * 16 + (l & 15);
            int kb = kk * 32 + ((l >> 4) << 3);
            short8 v;
            #pragma unroll
            for (int i = 0; i < 8; ++i) v[i] = f2bf(W1[(kb + i) * HID + col]);
            *(short8*)(W1P + (((kk * 4 + c) * 64) + l) * 8) = v;
        }
    } else if (b < 256) {          // W2 (64x1024) -> W2P[kk2<2][ct<64][l][8]
        if (t < 64) {
            int bb = b - 128;
            int kk2 = bb >> 6, ct = bb & 63;
            int col = ct * 16 + (l & 15);
            int kb = kk2 * 32 + ((l >> 4) << 3);
            short8 v;
            #pragma unroll
            for (int i = 0; i < 8; ++i) v[i] = f2bf(W2[(kb + i) * DM + col]);
            *(short8*)(W2P + (((kk2 * 64 + ct) * 64) + l) * 8) = v;
        }
    } else if (b < 320) {          // G[j][i] = sum_d W2[j][d]*W1[d][i]; j = b-256
        int j = b - 256;
        float acc = 0.f;
        #pragma unroll 8
        for (int d = q4 * 256; d < q4 * 256 + 256; ++d)
            acc += W2[j * DM + d] * W1[d * HID + l];
        red[q4][l] = acc;
        __syncthreads();
        if (t < 64) {
            float a = red[0][l] + red[1][l] + red[2][l] + red[3][l];
            int kk = j >> 5, lk = (j >> 3) & 3, ii = j & 7, c = l >> 4, lo = l & 15;
            GP[(((kk * 4 + c) * 64) + lk * 16 + lo) * 8 + ii] = f2bf(a);
        }
    } else {                       // u[i] = sum_d b2[d]*W1[d][i]
        float acc = 0.f;
        #pragma unroll 8
        for (int d = q4 * 256; d < q4 * 256 + 256; ++d)
            acc += b2[d] * W1[d * HID + l];
        red[q4][l] = acc;
        __syncthreads();
        if (t < 64) U[l] = red[0][l] + red[1][l] + red[2][l] + red[3][l];
    }
}

// ---------------- fused RK4 neural-ODE kernel ----------------
// Block: 256 thr (4 waves), owns 16 rows of z for all 6 RK4 steps.
// z master = plain f32 in LDS (XOR-swizzled, 16B granule) — no hi/lo
// residual, no per-lane state arrays (R4/R5 spill lesson). P1 converts
// f32->bf16 on the fly (v_cvt_pk, cheap); P6 is a thin f32 RMW.
// Wave w: GEMM1/stages hid col-tile w (16 cols); GEMM2 cols [w*256,+256).
// MFMA: A = packed weights (M = out-col), B = z/H rows (N = row).
// D: m = (lane>>4)*4+reg (out-col), n = lane&15 (row).
// amdgpu_waves_per_eu(2,4): R3-proven — prevents the 8-wave heuristic
// from capping at 64 VGPR and spilling; LDS binds at 2 blocks/CU anyway.
__global__ __launch_bounds__(256) __attribute__((amdgpu_waves_per_eu(2, 4)))
void k_ode(
        const float* __restrict__ X, const float* __restrict__ W1,
        const float* __restrict__ b1, const float* __restrict__ b2,
        const short* __restrict__ W1P, const short* __restrict__ W2P,
        const short* __restrict__ GP, const float* __restrict__ U,
        float* __restrict__ OUT) {
    extern __shared__ char smem[];
    const int t = threadIdx.x;
    const int lane = t & 63;
    const int w = t >> 6;                    // 0..3
    const int hq = lane >> 4;
    const int l15 = lane & 15;
    const int hcol0 = w * 16 + hq * 4;       // hid-col base (stage epilogues)
    const size_t row0 = (size_t)blockIdx.x * 16;
    const int swz = (l15 & 7) << 4;          // row XOR swizzle, 16B granule
    const int zrow = l15 << 12;              // row byte base in zf32 (pitch 4096)

    // per-lane persistent constants (L2-hot broadcasts)
    f32x4 u4   = *(const f32x4*)(U + hcol0);
    f32x4 b14  = *(const f32x4*)(b1 + hcol0);
    f32x4 w1t4 = *(const f32x4*)(W1 + DM * HID + hcol0);   // time row of W1
    short8 gf0 = *(const short8*)(GP + (w * 64 + lane) * 8);
    short8 gf1 = *(const short8*)(GP + ((4 + w) * 64 + lane) * 8);

    // ---- stage b2 into LDS; load x -> zf32 LDS (swizzled) ----
    *(f32x4*)(smem + L_B2 + t * 16) = *(const f32x4*)(b2 + t * 4);
    {
        int r = t >> 4, c16 = t & 15;
        int swr = (r & 7) << 4;
        const f32x4* xs = (const f32x4*)(X + (row0 + r) * DM);
        #pragma unroll 4
        for (int jj = 0; jj < 16; ++jj) {
            int cc = c16 + 16 * jj;          // f32x4 chunk index in row
            f32x4 v = xs[cc];
            *(f32x4*)(smem + L_ZF + (((r << 12) + (cc << 4)) ^ swr)) = v;
        }
    }
    BAR();

    for (int s = 0; s < NSTEP; ++s) {
        const float tcur = RSTEP * (float)s;

        // P1: sz = (z @ W1k) tile; K=1024 in 32 slices, dual chains.
        // z frag: 2x ds_read_b128 f32 + packed cvt to bf16.
        f32x4 sz;
        {
            const short8* wp = (const short8*)W1P + (w * 64 + lane);
            f32x4 a0 = (f32x4){0.f, 0.f, 0.f, 0.f};
            f32x4 a1 = (f32x4){0.f, 0.f, 0.f, 0.f};
            #pragma unroll 4
            for (int kk = 0; kk < 32; kk += 2) {
                int base = zrow + (kk << 7) + (hq << 5);
                f32x4 lo0 = *(const f32x4*)(smem + L_ZF + ((base      ) ^ swz));
                f32x4 hi0 = *(const f32x4*)(smem + L_ZF + ((base +  16) ^ swz));
                f32x4 lo1 = *(const f32x4*)(smem + L_ZF + ((base + 128) ^ swz));
                f32x4 hi1 = *(const f32x4*)(smem + L_ZF + ((base + 144) ^ swz));
                short8 zf0, zf1;
                #pragma unroll
                for (int j = 0; j < 4; ++j) {
                    zf0[j] = f2bf(lo0[j]); zf0[4 + j] = f2bf(hi0[j]);
                    zf1[j] = f2bf(lo1[j]); zf1[4 + j] = f2bf(hi1[j]);
                }
                a0 = __builtin_amdgcn_mfma_f32_16x16x32_bf16(wp[kk * 256],       zf0, a0, 0, 0, 0);
                a1 = __builtin_amdgcn_mfma_f32_16x16x32_bf16(wp[(kk + 1) * 256], zf1, a1, 0, 0, 0);
            }
            sz = a0 + a1;
        }

        // P2: stage 1  H1 = tanh(sz + t*w1t + b1)
        f32x4 hsum;
        {
            short4v hc;
            #pragma unroll
            for (int j = 0; j < 4; ++j) {
                float T = sz[j] + tcur * w1t4[j] + b14[j];
                float h = ftanh(T);
                hsum[j] = h;
                hc[j] = f2bf(h);
            }
            *(short4v*)(smem + L_H0 + l15 * HP + hcol0 * 2) = hc;
        }
        BAR();

        // P3..P5: stages 2..4 via tiny H@G GEMM (G = W2@W1k)
        #pragma unroll
        for (int st = 0; st < 3; ++st) {
            const float c_i = (st == 2) ? RSTEP : (0.5f * RSTEP);
            const float t_i = tcur + ((st == 2) ? RSTEP : (0.5f * RSTEP));
            const float w_i = (st == 2) ? 1.f : 2.f;
            const int rbuf = (st & 1) ? L_H1 : L_H0;
            const int wbuf = (st & 1) ? L_H0 : L_H1;

            f32x4 dd = (f32x4){0.f, 0.f, 0.f, 0.f};
            {
                short8 hf0 = *(const short8*)(smem + rbuf + l15 * HP + (hq << 4));
                short8 hf1 = *(const short8*)(smem + rbuf + l15 * HP + 64 + (hq << 4));
                dd = __builtin_amdgcn_mfma_f32_16x16x32_bf16(gf0, hf0, dd, 0, 0, 0);
                dd = __builtin_amdgcn_mfma_f32_16x16x32_bf16(gf1, hf1, dd, 0, 0, 0);
            }
            short4v hc;
            #pragma unroll
            for (int j = 0; j < 4; ++j) {
                float T = sz[j] + c_i * (dd[j] + u4[j]) + t_i * w1t4[j] + b14[j];
                float h = ftanh(T);
                hsum[j] += w_i * h;
                hc[j] = f2bf(h);
            }
            if (st < 2) {
                *(short4v*)(smem + wbuf + l15 * HP + hcol0 * 2) = hc;
            } else {   // Hb = (h/6) * Hsum, GEMM2 B-operand
                short4v hb4;
                #pragma unroll
                for (int j = 0; j < 4; ++j) hb4[j] = f2bf(hsum[j] * (RSTEP / 6.f));
                *(short4v*)(smem + L_HB + l15 * HP + hcol0 * 2) = hb4;
            }
            BAR();
        }

        // P6: z += Hb @ W2 + h*b2   (wave w owns cols [w*256, +256))
        // Thin f32 RMW: ds_read_b128 z, 4 add + 4 fma, ds_write_b128.
        {
            short8 hb0 = *(const short8*)(smem + L_HB + l15 * HP + (hq << 4));
            short8 hb1 = *(const short8*)(smem + L_HB + l15 * HP + 64 + (hq << 4));
            const short8* w2p8 = (const short8*)W2P;

            if (s < NSTEP - 1) {
                #pragma unroll
                for (int q = 0; q < 16; ++q) {
                    int ct = w * 16 + q;
                    short8 wa = w2p8[ct * 64 + lane];
                    short8 wb = w2p8[(64 + ct) * 64 + lane];
                    f32x4 p = (f32x4){0.f, 0.f, 0.f, 0.f};
                    p = __builtin_amdgcn_mfma_f32_16x16x32_bf16(wa, hb0, p, 0, 0, 0);
                    p = __builtin_amdgcn_mfma_f32_16x16x32_bf16(wb, hb1, p, 0, 0, 0);
                    int colb = (w << 10) + (q << 6) + (hq << 4);  // byte col
                    int za = (zrow + colb) ^ swz;
                    f32x4 zv  = *(const f32x4*)(smem + L_ZF + za);
                    f32x4 b2v = *(const f32x4*)(smem + L_B2 + colb);
                    f32x4 nv;
                    #pragma unroll
                    for (int j = 0; j < 4; ++j)
                        nv[j] = zv[j] + p[j] + RSTEP * b2v[j];
                    *(f32x4*)(smem + L_ZF + za) = nv;
                }
            } else {   // last step: final z straight to OUT (f32)
                float* orow = OUT + (row0 + l15) * DM;
                #pragma unroll
                for (int q = 0; q < 16; ++q) {
                    int ct = w * 16 + q;
                    short8 wa = w2p8[ct * 64 + lane];
                    short8 wb = w2p8[(64 + ct) * 64 + lane];
                    f32x4 p = (f32x4){0.f, 0.f, 0.f, 0.f};
                    p = __builtin_amdgcn_mfma_f32_16x16x32_bf16(wa, hb0, p, 0, 0, 0);
                    p = __builtin_amdgcn_mfma_f32_16x16x32_bf16(wb, hb1, p, 0, 0, 0);
                    int colb = (w << 10) + (q << 6) + (hq << 4);
                    f32x4 zv  = *(const f32x4*)(smem + L_ZF + ((zrow + colb) ^ swz));
                    f32x4 b2v = *(const f32x4*)(smem + L_B2 + colb);
                    f32x4 nv;
                    #pragma unroll
                    for (int j = 0; j < 4; ++j)
                        nv[j] = zv[j] + p[j] + RSTEP * b2v[j];
                    *(f32x4*)(orow + (colb >> 2)) = nv;
                }
            }
        }
        if (s < NSTEP - 1) BAR();
    }
}

extern "C" void kernel_launch(void* const* d_in, const int* in_sizes, int n_in,
                              void* d_out, int out_size, void* d_ws, size_t ws_size,
                              hipStream_t stream) {
    (void)in_sizes; (void)n_in; (void)out_size; (void)ws_size;
    const float* X  = (const float*)d_in[0];
    const float* W1 = (const float*)d_in[1];
    const float* b1 = (const float*)d_in[2];
    const float* W2 = (const float*)d_in[3];
    const float* b2 = (const float*)d_in[4];
    float* OUT = (float*)d_out;
    short* W1P = (short*)((char*)d_ws + WS_W1P);
    short* W2P = (short*)((char*)d_ws + WS_W2P);
    short* GP  = (short*)((char*)d_ws + WS_GP);
    float* U   = (float*)((char*)d_ws + WS_U);

    // 76.5 KiB dynamic LDS (> 64 KiB default cap)
    hipFuncSetAttribute(reinterpret_cast<const void*>(k_ode),
                        hipFuncAttributeMaxDynamicSharedMemorySize, LDS_TOTAL);

    k_prep<<<321, 256, 0, stream>>>(W1, W2, b2, W1P, W2P, GP, U);
    k_ode<<<1024, 256, LDS_TOTAL, stream>>>(X, W1, b1, b2, W1P, W2P, GP, U, OUT);
}

// Round 7
// 120.434 us; speedup vs baseline: 5.4755x; 1.2636x over previous
//
#include <hip/hip_runtime.h>
#include <hip/hip_bf16.h>

#define DM 1024
#define HID 64
#define NSTEP 6
#define RSTEP (1.0f/6.0f)

using short8  = __attribute__((ext_vector_type(8))) short;
using short4v = __attribute__((ext_vector_type(4))) short;
using f32x4   = __attribute__((ext_vector_type(4))) float;

// workspace byte offsets
#define WS_W1P 0          // 1024x64 bf16 packed A-frags (131072 B)
#define WS_W2P 131072     // 64x1024 bf16 packed A-frags (131072 B)
#define WS_GP  262144     // 64x64 bf16 packed A-frags (8192 B)
#define WS_U   270336     // 64 f32  (u = b2 @ W1k)

// LDS byte offsets (total 11008 B -> occupancy VGPR-bound, ~4 blocks/CU)
#define L_H0 0            // H ping  [16][72] bf16, pitch 144 (2304)
#define L_H1 2304         // H pong
#define L_HB 4608         // Hb = (h/6)*Hsum
#define L_B2 6912         // b2 staged f32[1024] (4096)
#define LDS_TOTAL 11008
#define HP 144

// LDS-only barrier: order LDS ops, do NOT drain vmcnt (weight loads stay
// in flight across barriers; cross-wave data passes only through LDS).
#define BAR() asm volatile("s_waitcnt lgkmcnt(0)\n\ts_barrier" ::: "memory")

__device__ __forceinline__ short f2bf(float f) {   // RNE via HW cvt
    __hip_bfloat16 h = __float2bfloat16(f);
    short s;
    __builtin_memcpy(&s, &h, 2);
    return s;
}
__device__ __forceinline__ float ftanh(float x) {
    x = fminf(fmaxf(x, -10.f), 10.f);
    float e = __expf(2.f * x);
    return __fdividef(e - 1.f, e + 1.f);
}

// ---------------- prep: pack weights to MFMA fragment layout ----------------
// A-frag layout for mfma_f32_16x16x32_bf16: lane l holds M-row (l&15),
// k = (l>>4)*8 + i (8 consecutive k). Packed so each lane loads one short8.
__global__ void k_prep(const float* __restrict__ W1, const float* __restrict__ W2,
                       const float* __restrict__ b2,
                       short* __restrict__ W1P, short* __restrict__ W2P,
                       short* __restrict__ GP, float* __restrict__ U) {
    __shared__ float red[4][64];
    int b = blockIdx.x;
    int t = threadIdx.x;           // 256 threads
    int l = t & 63, q4 = t >> 6;
    if (b < 128) {                 // W1k (1024x64) -> W1P[kk<32][c<4][l][8]
        if (t < 64) {
            int kk = b >> 2, c = b & 3;
            int col = c * 16 + (l & 15);
            int kb = kk * 32 + ((l >> 4) << 3);
            short8 v;
            #pragma unroll
            for (int i = 0; i < 8; ++i) v[i] = f2bf(W1[(kb + i) * HID + col]);
            *(short8*)(W1P + (((kk * 4 + c) * 64) + l) * 8) = v;
        }
    } else if (b < 256) {          // W2 (64x1024) -> W2P[kk2<2][ct<64][l][8]
        if (t < 64) {
            int bb = b - 128;
            int kk2 = bb >> 6, ct = bb & 63;
            int col = ct * 16 + (l & 15);
            int kb = kk2 * 32 + ((l >> 4) << 3);
            short8 v;
            #pragma unroll
            for (int i = 0; i < 8; ++i) v[i] = f2bf(W2[(kb + i) * DM + col]);
            *(short8*)(W2P + (((kk2 * 64 + ct) * 64) + l) * 8) = v;
        }
    } else if (b < 320) {          // G[j][i] = sum_d W2[j][d]*W1[d][i]; j = b-256
        int j = b - 256;
        float acc = 0.f;
        #pragma unroll 8
        for (int d = q4 * 256; d < q4 * 256 + 256; ++d)
            acc += W2[j * DM + d] * W1[d * HID + l];
        red[q4][l] = acc;
        __syncthreads();
        if (t < 64) {
            float a = red[0][l] + red[1][l] + red[2][l] + red[3][l];
            int kk = j >> 5, lk = (j >> 3) & 3, ii = j & 7, c = l >> 4, lo = l & 15;
            GP[(((kk * 4 + c) * 64) + lk * 16 + lo) * 8 + ii] = f2bf(a);
        }
    } else {                       // u[i] = sum_d b2[d]*W1[d][i]
        float acc = 0.f;
        #pragma unroll 8
        for (int d = q4 * 256; d < q4 * 256 + 256; ++d)
            acc += b2[d] * W1[d * HID + l];
        red[q4][l] = acc;
        __syncthreads();
        if (t < 64) U[l] = red[0][l] + red[1][l] + red[2][l] + red[3][l];
    }
}

// ---------------- fused RK4 neural-ODE kernel (incremental sz) ----------------
// Key algebra: sz := z@W1k is maintained INCREMENTALLY in f32 registers:
//   sz' = sz + Hb@G + h*u      (G = W2@W1k, u = b2@W1k, both precomputed)
// so the big per-step GEMM1 is gone; it runs ONCE in the prologue (x@W1k,
// B-frags read straight from global). z itself lives in f32 REGISTERS
// (wave-private cols, z[16] statically indexed); LDS holds only the tiny
// H exchange buffers + b2. 4 barriers/step; P6 is barrier-free.
// Block: 256 thr (4 waves), 16 rows. Wave w: stage col-tile w (16 hid);
// P6/z cols [w*256,+256).
// MFMA: A = packed weights (M = out-col), B = z/H rows (N = row).
// D: m = (lane>>4)*4+reg (out-col), n = lane&15 (row).
__global__ __launch_bounds__(256) __attribute__((amdgpu_waves_per_eu(2, 4)))
void k_ode(
        const float* __restrict__ X, const float* __restrict__ W1,
        const float* __restrict__ b1, const float* __restrict__ b2,
        const short* __restrict__ W1P, const short* __restrict__ W2P,
        const short* __restrict__ GP, const float* __restrict__ U,
        float* __restrict__ OUT) {
    extern __shared__ char smem[];
    const int t = threadIdx.x;
    const int lane = t & 63;
    const int w = t >> 6;                    // 0..3
    const int hq = lane >> 4;
    const int l15 = lane & 15;
    const int hcol0 = w * 16 + hq * 4;       // hid-col base (stage epilogues)
    const size_t row0 = (size_t)blockIdx.x * 16;
    const float* xrow = X + (row0 + l15) * DM;

    // per-lane persistent constants (L2-hot broadcasts)
    f32x4 u4   = *(const f32x4*)(U + hcol0);
    f32x4 b14  = *(const f32x4*)(b1 + hcol0);
    f32x4 w1t4 = *(const f32x4*)(W1 + DM * HID + hcol0);   // time row of W1
    short8 gf0 = *(const short8*)(GP + (w * 64 + lane) * 8);
    short8 gf1 = *(const short8*)(GP + ((4 + w) * 64 + lane) * 8);

    // stage b2 -> LDS (first read is after stage1's barrier; no BAR needed)
    *(f32x4*)(smem + L_B2 + t * 16) = *(const f32x4*)(b2 + t * 4);

    // ---- z master: lane owns row l15, cols w*256 + q*16 + hq*4 (+j) ----
    f32x4 z[16];
    #pragma unroll
    for (int q = 0; q < 16; ++q)
        z[q] = *(const f32x4*)(xrow + w * 256 + q * 16 + hq * 4);

    // ---- prologue GEMM1 (once): sz = x @ W1k, x B-frags from global ----
    f32x4 sz;
    {
        const short8* wp = (const short8*)W1P + (w * 64 + lane);
        f32x4 a0 = (f32x4){0.f, 0.f, 0.f, 0.f};
        f32x4 a1 = (f32x4){0.f, 0.f, 0.f, 0.f};
        #pragma unroll 4
        for (int kk = 0; kk < 32; kk += 2) {
            const float* xp = xrow + (kk << 5) + (hq << 3);
            f32x4 lo0 = *(const f32x4*)(xp);
            f32x4 hi0 = *(const f32x4*)(xp + 4);
            f32x4 lo1 = *(const f32x4*)(xp + 32);
            f32x4 hi1 = *(const f32x4*)(xp + 36);
            short8 zf0, zf1;
            #pragma unroll
            for (int j = 0; j < 4; ++j) {
                zf0[j] = f2bf(lo0[j]); zf0[4 + j] = f2bf(hi0[j]);
                zf1[j] = f2bf(lo1[j]); zf1[4 + j] = f2bf(hi1[j]);
            }
            a0 = __builtin_amdgcn_mfma_f32_16x16x32_bf16(wp[kk * 256],       zf0, a0, 0, 0, 0);
            a1 = __builtin_amdgcn_mfma_f32_16x16x32_bf16(wp[(kk + 1) * 256], zf1, a1, 0, 0, 0);
        }
        sz = a0 + a1;
    }

    for (int s = 0; s < NSTEP; ++s) {
        const float tcur = RSTEP * (float)s;

        // stage 1: H1 = tanh(sz + t*w1t + b1)   (pure registers -> H0)
        f32x4 hsum;
        {
            short4v hc;
            #pragma unroll
            for (int j = 0; j < 4; ++j) {
                float T = sz[j] + tcur * w1t4[j] + b14[j];
                float h = ftanh(T);
                hsum[j] = h;
                hc[j] = f2bf(h);
            }
            *(short4v*)(smem + L_H0 + l15 * HP + hcol0 * 2) = hc;
        }
        BAR();

        // stages 2..4 via tiny H@G GEMM (G = W2@W1k)
        #pragma unroll
        for (int st = 0; st < 3; ++st) {
            const float c_i = (st == 2) ? RSTEP : (0.5f * RSTEP);
            const float t_i = tcur + ((st == 2) ? RSTEP : (0.5f * RSTEP));
            const float w_i = (st == 2) ? 1.f : 2.f;
            const int rbuf = (st & 1) ? L_H1 : L_H0;
            const int wbuf = (st & 1) ? L_H0 : L_H1;

            short8 hf0 = *(const short8*)(smem + rbuf + l15 * HP + (hq << 4));
            short8 hf1 = *(const short8*)(smem + rbuf + l15 * HP + 64 + (hq << 4));
            f32x4 dd = (f32x4){0.f, 0.f, 0.f, 0.f};
            dd = __builtin_amdgcn_mfma_f32_16x16x32_bf16(gf0, hf0, dd, 0, 0, 0);
            dd = __builtin_amdgcn_mfma_f32_16x16x32_bf16(gf1, hf1, dd, 0, 0, 0);
            short4v hc;
            #pragma unroll
            for (int j = 0; j < 4; ++j) {
                float T = sz[j] + c_i * (dd[j] + u4[j]) + t_i * w1t4[j] + b14[j];
                float h = ftanh(T);
                hsum[j] += w_i * h;
                hc[j] = f2bf(h);
            }
            if (st < 2) {
                *(short4v*)(smem + wbuf + l15 * HP + hcol0 * 2) = hc;
            } else {   // Hb = (h/6) * Hsum, GEMM2 B-operand
                short4v hb4;
                #pragma unroll
                for (int j = 0; j < 4; ++j) hb4[j] = f2bf(hsum[j] * (RSTEP / 6.f));
                *(short4v*)(smem + L_HB + l15 * HP + hcol0 * 2) = hb4;
            }
            BAR();
        }

        // P6 (barrier-free): z += Hb @ W2 + h*b2 ; sz += Hb @ G + h*u
        {
            short8 hb0 = *(const short8*)(smem + L_HB + l15 * HP + (hq << 4));
            short8 hb1 = *(const short8*)(smem + L_HB + l15 * HP + 64 + (hq << 4));
            const short8* w2p8 = (const short8*)W2P;

            if (s < NSTEP - 1) {
                #pragma unroll
                for (int q = 0; q < 16; ++q) {
                    int ct = w * 16 + q;
                    short8 wa = w2p8[ct * 64 + lane];
                    short8 wb = w2p8[(64 + ct) * 64 + lane];
                    f32x4 p = (f32x4){0.f, 0.f, 0.f, 0.f};
                    p = __builtin_amdgcn_mfma_f32_16x16x32_bf16(wa, hb0, p, 0, 0, 0);
                    p = __builtin_amdgcn_mfma_f32_16x16x32_bf16(wb, hb1, p, 0, 0, 0);
                    int colb = (w << 10) + (q << 6) + (hq << 4);  // byte col
                    f32x4 b2v = *(const f32x4*)(smem + L_B2 + colb);
                    #pragma unroll
                    for (int j = 0; j < 4; ++j)
                        z[q][j] += p[j] + RSTEP * b2v[j];
                }
                // incremental sz update (reuses hb frags; 2 MFMAs)
                f32x4 d = (f32x4){0.f, 0.f, 0.f, 0.f};
                d = __builtin_amdgcn_mfma_f32_16x16x32_bf16(gf0, hb0, d, 0, 0, 0);
                d = __builtin_amdgcn_mfma_f32_16x16x32_bf16(gf1, hb1, d, 0, 0, 0);
                #pragma unroll
                for (int j = 0; j < 4; ++j)
                    sz[j] += d[j] + RSTEP * u4[j];
            } else {   // last step: final z straight from regs to OUT (f32)
                float* orow = OUT + (row0 + l15) * DM;
                #pragma unroll
                for (int q = 0; q < 16; ++q) {
                    int ct = w * 16 + q;
                    short8 wa = w2p8[ct * 64 + lane];
                    short8 wb = w2p8[(64 + ct) * 64 + lane];
                    f32x4 p = (f32x4){0.f, 0.f, 0.f, 0.f};
                    p = __builtin_amdgcn_mfma_f32_16x16x32_bf16(wa, hb0, p, 0, 0, 0);
                    p = __builtin_amdgcn_mfma_f32_16x16x32_bf16(wb, hb1, p, 0, 0, 0);
                    int colb = (w << 10) + (q << 6) + (hq << 4);
                    f32x4 b2v = *(const f32x4*)(smem + L_B2 + colb);
                    f32x4 nv;
                    #pragma unroll
                    for (int j = 0; j < 4; ++j)
                        nv[j] = z[q][j] + p[j] + RSTEP * b2v[j];
                    *(f32x4*)(orow + (colb >> 2)) = nv;
                }
            }
        }
        // no barrier: next stage1 is wave-local; H0 write races nothing
        // (all waves passed the stage4 barrier; P6 touches only L_HB/L_B2).
    }
}

extern "C" void kernel_launch(void* const* d_in, const int* in_sizes, int n_in,
                              void* d_out, int out_size, void* d_ws, size_t ws_size,
                              hipStream_t stream) {
    (void)in_sizes; (void)n_in; (void)out_size; (void)ws_size;
    const float* X  = (const float*)d_in[0];
    const float* W1 = (const float*)d_in[1];
    const float* b1 = (const float*)d_in[2];
    const float* W2 = (const float*)d_in[3];
    const float* b2 = (const float*)d_in[4];
    float* OUT = (float*)d_out;
    short* W1P = (short*)((char*)d_ws + WS_W1P);
    short* W2P = (short*)((char*)d_ws + WS_W2P);
    short* GP  = (short*)((char*)d_ws + WS_GP);
    float* U   = (float*)((char*)d_ws + WS_U);

    k_prep<<<321, 256, 0, stream>>>(W1, W2, b2, W1P, W2P, GP, U);
    k_ode<<<1024, 256, LDS_TOTAL, stream>>>(X, W1, b1, b2, W1P, W2P, GP, U, OUT);
}